// Round 19
// baseline (142.466 us; speedup 1.0000x reference)
//
#include <hip/hip_runtime.h>
#include <hip/hip_bf16.h>

#define S_LEN 2048
#define HID_DIM 1024
#define NH 16
#define HD 64
#define MTOT 4096  // B*S

typedef __attribute__((ext_vector_type(8))) short short8;
typedef __attribute__((ext_vector_type(4))) float f32x4;

__device__ __forceinline__ float bf2f(unsigned short u) {
  union { unsigned int i; float f; } x; x.i = ((unsigned int)u) << 16; return x.f;
}
__device__ __forceinline__ unsigned short f2bf(float f) {
  union { float ff; unsigned int i; } x; x.ff = f;
  return (unsigned short)((x.i + 0x7fffu + ((x.i >> 16) & 1u)) >> 16);
}
__device__ __forceinline__ unsigned short f2bf_rna(float f) {  // f >= 0 only
  union { float ff; unsigned int i; } x; x.ff = f;
  return (unsigned short)((x.i + 0x8000u) >> 16);
}
__device__ __forceinline__ f32x4 mfma16(short8 a, short8 b, f32x4 c) {
  return __builtin_amdgcn_mfma_f32_16x16x32_bf16(a, b, c, 0, 0, 0);
}
__device__ __forceinline__ void gl_lds16(const unsigned short* g, unsigned short* l) {
  __builtin_amdgcn_global_load_lds(
      (const __attribute__((address_space(1))) unsigned int*)g,
      (__attribute__((address_space(3))) unsigned int*)l, 16, 0, 0);
}

// ---------------- single fused f32 -> bf16 convert (grid-stride, 7 buffers) ----------------
#define CVT_N4 4194304
__global__ __launch_bounds__(256) void cvt_all(
    const float* __restrict__ fq, const float* __restrict__ fk, const float* __restrict__ fv,
    const float* __restrict__ Wq, const float* __restrict__ Wk, const float* __restrict__ Wv,
    const float* __restrict__ Wo,
    unsigned short* __restrict__ cq, unsigned short* __restrict__ ck,
    unsigned short* __restrict__ cv, unsigned short* __restrict__ wqb,
    unsigned short* __restrict__ wkb, unsigned short* __restrict__ wvb,
    unsigned short* __restrict__ wob) {
  for (int i = blockIdx.x * 256 + threadIdx.x; i < CVT_N4; i += gridDim.x * 256) {
    const float4* s; unsigned long long* d; int off;
    if (i < 3145728) {
      if (i < 1048576)      { s = (const float4*)fq; d = (unsigned long long*)cq; off = i; }
      else if (i < 2097152) { s = (const float4*)fk; d = (unsigned long long*)ck; off = i - 1048576; }
      else                  { s = (const float4*)fv; d = (unsigned long long*)cv; off = i - 2097152; }
    } else {
      const int wi = i - 3145728;
      if (wi < 262144)      { s = (const float4*)Wq; d = (unsigned long long*)wqb; off = wi; }
      else if (wi < 524288) { s = (const float4*)Wk; d = (unsigned long long*)wkb; off = wi - 262144; }
      else if (wi < 786432) { s = (const float4*)Wv; d = (unsigned long long*)wvb; off = wi - 524288; }
      else                  { s = (const float4*)Wo; d = (unsigned long long*)wob; off = wi - 786432; }
    }
    float4 v = s[off];
    union { unsigned short u[4]; unsigned long long ll; } o;
    o.u[0] = f2bf(v.x); o.u[1] = f2bf(v.y); o.u[2] = f2bf(v.z); o.u[3] = f2bf(v.w);
    d[off] = o.ll;
  }
}

// ---------------- GEMM core: C[128x128] += A[128xK] * W[128xK]^T ----------------
__device__ __forceinline__ void gemm_core(const unsigned short* __restrict__ A,
                                          const unsigned short* __restrict__ W,
                                          unsigned short* As, unsigned short* Bs,
                                          int m0, int n0, f32x4 (&acc)[4][4]) {
  const int tid = threadIdx.x;
  const int lane = tid & 63;
  const int wrow = (tid >> 6) >> 1, wcol = (tid >> 6) & 1;
  const int lr = lane & 15, g = lane >> 4;
  const int r32 = tid >> 3;                     // 0..31
  const int cph = (tid & 7) ^ (r32 & 7);        // swizzled source chunk
  const unsigned short* ag = A + (size_t)(m0 + r32) * HID_DIM + cph * 8;
  const unsigned short* bg = W + (size_t)(n0 + r32) * HID_DIM + cph * 8;
  unsigned short* al = As + tid * 8;
  unsigned short* bl = Bs + tid * 8;
  for (int k0 = 0; k0 < HID_DIM; k0 += 64) {
    __syncthreads();
#pragma unroll
    for (int p = 0; p < 4; ++p) {
      gl_lds16(ag + (size_t)(p * 32) * HID_DIM + k0, al + p * 2048);
      gl_lds16(bg + (size_t)(p * 32) * HID_DIM + k0, bl + p * 2048);
    }
    __syncthreads();
#pragma unroll
    for (int ks = 0; ks < 2; ++ks) {
      short8 af[4], bfr[4];
#pragma unroll
      for (int m = 0; m < 4; ++m)
        af[m] = *reinterpret_cast<const short8*>(
            &As[(wrow * 64 + m * 16 + lr) * 64 + (((ks * 4 + g) ^ (lr & 7)) * 8)]);
#pragma unroll
      for (int n = 0; n < 4; ++n)
        bfr[n] = *reinterpret_cast<const short8*>(
            &Bs[(wcol * 64 + n * 16 + lr) * 64 + (((ks * 4 + g) ^ (lr & 7)) * 8)]);
#pragma unroll
      for (int m = 0; m < 4; ++m)
#pragma unroll
        for (int n = 0; n < 4; ++n)
          acc[m][n] = mfma16(af[m], bfr[n], acc[m][n]);
    }
  }
}

// ---------------- fused QKV projection GEMM (Q pre-scaled by log2e/8) ----------------
__global__ __launch_bounds__(256, 4) void qkv_gemm(
    const unsigned short* __restrict__ Aq, const unsigned short* __restrict__ Ak,
    const unsigned short* __restrict__ Av,
    const unsigned short* __restrict__ Wq, const unsigned short* __restrict__ Wk,
    const unsigned short* __restrict__ Wv,
    const float* __restrict__ bq, const float* __restrict__ bk, const float* __restrict__ bv,
    unsigned short* __restrict__ Qp, unsigned short* __restrict__ Kp,
    unsigned short* __restrict__ Vt) {
  __shared__ __attribute__((aligned(16))) unsigned short As[128 * 64];
  __shared__ __attribute__((aligned(16))) unsigned short Bs[128 * 64];
  const int bid = blockIdx.x;            // 0..767
  const int xcd = bid & 7;
  const int j = bid >> 3;                // 0..95 local to XCD
  const int G = xcd * 12 + (j >> 3);     // global (which,m0) group 0..95
  const int which = G >> 5;              // 0:Q 1:K 2:V
  const int m0 = (G & 31) * 128;
  const int n0 = (j & 7) * 128;
  const unsigned short* A = which == 0 ? Aq : which == 1 ? Ak : Av;
  const unsigned short* W = which == 0 ? Wq : which == 1 ? Wk : Wv;
  const float* bias = which == 0 ? bq : which == 1 ? bk : bv;

  f32x4 acc[4][4];
  const f32x4 vzero = {0.f, 0.f, 0.f, 0.f};
#pragma unroll
  for (int m = 0; m < 4; ++m)
#pragma unroll
    for (int n = 0; n < 4; ++n) acc[m][n] = vzero;

  gemm_core(A, W, As, Bs, m0, n0, acc);

  const int lane = threadIdx.x & 63;
  const int wrow = (threadIdx.x >> 6) >> 1, wcol = (threadIdx.x >> 6) & 1;
  const int lr = lane & 15, g = lane >> 4;
  const float scl = (which == 0) ? 0.125f * 1.44269504f : 1.0f;
#pragma unroll
  for (int m = 0; m < 4; ++m) {
    const int rbase = m0 + wrow * 64 + m * 16 + g * 4;
#pragma unroll
    for (int n = 0; n < 4; ++n) {
      const int col = n0 + wcol * 64 + n * 16 + lr;
      const float bcol = bias[col];
      if (which < 2) {
        unsigned short* O = which == 0 ? Qp : Kp;
#pragma unroll
        for (int rg = 0; rg < 4; ++rg)
          O[(size_t)(rbase + rg) * HID_DIM + col] = f2bf((acc[m][n][rg] + bcol) * scl);
      } else {
        const int bb = rbase >> 11, s = rbase & 2047;
        const int h = col >> 6, d = col & 63;
        union { unsigned short u[4]; unsigned long long ll; } o;
#pragma unroll
        for (int rg = 0; rg < 4; ++rg) o.u[rg] = f2bf(acc[m][n][rg] + bcol);
        *reinterpret_cast<unsigned long long*>(
            &Vt[((size_t)(bb * NH + h) * HD + d) * S_LEN + s]) = o.ll;
      }
    }
  }
}

// ---------------- output GEMM: 512-thread / 8-wave blocks (2x4 wave grid) ----------------
__global__ __launch_bounds__(512) void out_gemm(const unsigned short* __restrict__ X,
                                                const unsigned short* __restrict__ Wo,
                                                const float* __restrict__ bo,
                                                float* __restrict__ out) {
  __shared__ __attribute__((aligned(16))) unsigned short As[128 * 64];
  __shared__ __attribute__((aligned(16))) unsigned short Bs[128 * 64];
  const int bid = blockIdx.x;            // 0..255
  const int xcd = bid & 7;
  const int j = bid >> 3;                // 0..31
  const int m0 = (xcd * 4 + (j >> 3)) * 128;
  const int n0 = (j & 7) * 128;
  const int tid = threadIdx.x;
  const int lane = tid & 63;
  const int w = tid >> 6;                // 0..7
  const int wrow = w >> 2;               // 0..1 : 64-row half
  const int wcol = w & 3;                // 0..3 : 32-col quarter
  const int lr = lane & 15, g = lane >> 4;

  f32x4 acc[4][2];
  const f32x4 vzero = {0.f, 0.f, 0.f, 0.f};
#pragma unroll
  for (int m = 0; m < 4; ++m)
#pragma unroll
    for (int n = 0; n < 2; ++n) acc[m][n] = vzero;

  for (int k0 = 0; k0 < HID_DIM; k0 += 64) {
    __syncthreads();
#pragma unroll
    for (int p = 0; p < 2; ++p) {
      const int ci = p * 512 + tid;      // chunk index 0..1023
      const int row = ci >> 3, c = ci & 7;
      const int csrc = (c ^ (row & 7)) * 8;
      gl_lds16(X + (size_t)(m0 + row) * HID_DIM + csrc + k0, As + ci * 8);
      gl_lds16(Wo + (size_t)(n0 + row) * HID_DIM + csrc + k0, Bs + ci * 8);
    }
    __syncthreads();
#pragma unroll
    for (int ks = 0; ks < 2; ++ks) {
      short8 af[4], bfr[2];
#pragma unroll
      for (int m = 0; m < 4; ++m)
        af[m] = *reinterpret_cast<const short8*>(
            &As[(wrow * 64 + m * 16 + lr) * 64 + (((ks * 4 + g) ^ (lr & 7)) * 8)]);
#pragma unroll
      for (int n = 0; n < 2; ++n)
        bfr[n] = *reinterpret_cast<const short8*>(
            &Bs[(wcol * 32 + n * 16 + lr) * 64 + (((ks * 4 + g) ^ (lr & 7)) * 8)]);
#pragma unroll
      for (int m = 0; m < 4; ++m)
#pragma unroll
        for (int n = 0; n < 2; ++n)
          acc[m][n] = mfma16(af[m], bfr[n], acc[m][n]);
    }
  }

#pragma unroll
  for (int m = 0; m < 4; ++m) {
    const int rbase = m0 + wrow * 64 + m * 16 + g * 4;
#pragma unroll
    for (int n = 0; n < 2; ++n) {
      const int col = n0 + wcol * 32 + n * 16 + lr;
      const float bcol = bo[col];
#pragma unroll
      for (int rg = 0; rg < 4; ++rg)
        out[(size_t)(rbase + rg) * HID_DIM + col] = acc[m][n][rg] + bcol;
    }
  }
}

// ---------------- flash attention: + s_setprio around MFMA clusters (T5) ----------------
// CU hosts 2 independent blocks (phase-diverse) -> setprio has something to arbitrate.
__global__ __launch_bounds__(512, 2) void attn_kernel(
    const unsigned short* __restrict__ Qp, const unsigned short* __restrict__ Kp,
    const unsigned short* __restrict__ Vt, const float* __restrict__ relk,
    const float* __restrict__ relv, unsigned short* __restrict__ Xa) {
  __shared__ __attribute__((aligned(16))) unsigned short kv[2][8192];  // [buf][K 4096sh | V 4096sh]
  __shared__ __attribute__((aligned(16))) unsigned short Ps[8][16][72];
  __shared__ float projs[128][5];
  __shared__ float rvs[5][64];

  const int tid = threadIdx.x;
  const int lane = tid & 63;
  const int w = tid >> 6;          // 0..7
  const int lr = lane & 15, g = lane >> 4;
  const int virt = (blockIdx.x & 7) * 64 + (blockIdx.x >> 3);
  const int bh = virt >> 4;
  const int qbase = (virt & 15) * 128;
  const int b = bh >> 4, h = bh & 15;

  const unsigned short* Qg = Qp + ((size_t)(b * S_LEN + qbase)) * HID_DIM + h * HD;
  const unsigned short* Kg = Kp + ((size_t)b * S_LEN) * HID_DIM + h * HD;
  const unsigned short* Vg = Vt + (size_t)bh * HD * S_LEN;

  // ---- prologue: Q -> kv[1] (128 rows), K0/V0 -> kv[0]; swizzled-source gl_lds ----
#pragma unroll
  for (int i = 0; i < 2; ++i) {
    const int flat = i * 8192 + tid * 16;  // LDS byte
    const int row = flat >> 7, c = (flat >> 4) & 7;
    gl_lds16(Qg + (size_t)row * HID_DIM + ((c ^ (row & 7)) * 8), &kv[1][flat >> 1]);
  }
  {
    const int flat = tid * 16;             // 8 KB = one pass with 512 threads
    const int row = flat >> 7, c = (flat >> 4) & 7;
    const int csrc = (c ^ (row & 7)) * 8;
    gl_lds16(Kg + (size_t)row * HID_DIM + csrc, &kv[0][flat >> 1]);
    gl_lds16(Vg + (size_t)row * S_LEN + csrc, &kv[0][4096 + (flat >> 1)]);
  }
  for (int i = tid; i < 320; i += 512) ((float*)rvs)[i] = relv[i];
  __syncthreads();  // Q, K0, V0 staged (barrier drains vmcnt)

  // A-fragments of Q
  short8 aq[2];
#pragma unroll
  for (int h2 = 0; h2 < 2; ++h2) {
    const int row = w * 16 + lr;
    aq[h2] = *reinterpret_cast<const short8*>(
        &kv[1][row * 64 + (((g + 4 * h2) ^ (lr & 7)) * 8)]);
  }
  // projs via MFMA (B = relk rows j=lr<5, bf16; zero otherwise)
  {
    short8 rk0 = {0, 0, 0, 0, 0, 0, 0, 0}, rk1 = rk0;
    if (lr < 5) {
      const float* rp = relk + lr * 64 + g * 8;
#pragma unroll
      for (int e = 0; e < 8; ++e) {
        rk0[e] = (short)f2bf(rp[e]);
        rk1[e] = (short)f2bf(rp[e + 32]);
      }
    }
    const f32x4 vz = {0.f, 0.f, 0.f, 0.f};
    f32x4 pacc = mfma16(aq[0], rk0, vz);
    pacc = mfma16(aq[1], rk1, pacc);
    if (lr < 5) {
#pragma unroll
      for (int r = 0; r < 4; ++r) projs[w * 16 + g * 4 + r][lr] = pacc[r];
    }
  }
  __syncthreads();  // projs visible; Q reads done (kv[1] overwritten at t=0)

  float pj0[4], pj4[4];
#pragma unroll
  for (int i = 0; i < 4; ++i) {
    const int qloc = w * 16 + g * 4 + i;
    pj0[i] = projs[qloc][0];
    pj4[i] = projs[qloc][4];
  }
  f32x4 cinitL, cinitR;
#pragma unroll
  for (int i = 0; i < 4; ++i) { cinitL[i] = pj0[i]; cinitR[i] = pj4[i]; }

  const f32x4 vzero = {0.f, 0.f, 0.f, 0.f};
  f32x4 accO[4];
#pragma unroll
  for (int n = 0; n < 4; ++n) accO[n] = vzero;
  float sp0[4], sp4[4], sv1[4], sv2[4], sv3[4];
#pragma unroll
  for (int i = 0; i < 4; ++i) {
    sp0[i] = 0.f; sp4[i] = 0.f; sv1[i] = 0.f; sv2[i] = 0.f; sv3[i] = 0.f;
  }
  const int Qw = qbase + w * 16;  // wave's first q row (global)

  for (int t = 0; t < 32; ++t) {
    const int kb = t * 64;
    const unsigned short* Ks = kv[t & 1];
    const unsigned short* Vs = Ks + 4096;
    if (t < 31) {  // prefetch next tile into other buffer
      const int kb2 = kb + 64;
      unsigned short* dst = &kv[(t + 1) & 1][0];
      const int flat = tid * 16;
      const int row = flat >> 7, c = (flat >> 4) & 7;
      const int csrc = (c ^ (row & 7)) * 8;
      gl_lds16(Kg + (size_t)(kb2 + row) * HID_DIM + csrc, dst + (flat >> 1));
      gl_lds16(Vg + (size_t)row * S_LEN + kb2 + csrc, dst + 4096 + (flat >> 1));
    }
    const bool mixed = (kb + 63 >= Qw - 2) && (kb <= Qw + 17);
    const bool left = kb < Qw;
    const f32x4 ci = mixed ? vzero : (left ? cinitL : cinitR);
    // K fragments + QK^T (pj pre-added via C-init on non-mixed tiles)
    short8 kf[4][2];
#pragma unroll
    for (int n = 0; n < 4; ++n)
#pragma unroll
      for (int h2 = 0; h2 < 2; ++h2)
        kf[n][h2] = *reinterpret_cast<const short8*>(
            &Ks[(n * 16 + lr) * 64 + (((g + 4 * h2) ^ (lr & 7)) * 8)]);
    f32x4 accS[4];
    __builtin_amdgcn_s_setprio(1);  // T5: favor this wave through the MFMA cluster
#pragma unroll
    for (int n = 0; n < 4; ++n) {
      f32x4 z = mfma16(aq[0], kf[n][0], ci);
      accS[n] = mfma16(aq[1], kf[n][1], z);
    }
    __builtin_amdgcn_s_setprio(0);

    if (!mixed) {
#pragma unroll
      for (int n = 0; n < 4; ++n)
#pragma unroll
        for (int r = 0; r < 4; ++r) {
          const float p = __builtin_amdgcn_exp2f(accS[n][r]);
          if (left) sp0[r] += p; else sp4[r] += p;
          Ps[w][g * 4 + r][n * 16 + lr] = f2bf_rna(p);
        }
    } else {
#pragma unroll
      for (int n = 0; n < 4; ++n) {
        const int kg = kb + n * 16 + lr;
#pragma unroll
        for (int r = 0; r < 4; ++r) {
          const int qloc = w * 16 + g * 4 + r;
          const int dist = kg - (qbase + qloc);
          float pjv;
          if (dist <= -2) pjv = pj0[r];
          else if (dist >= 2) pjv = pj4[r];
          else pjv = projs[qloc][dist + 2];
          const float p = __builtin_amdgcn_exp2f(accS[n][r] + pjv);
          if (dist <= -2) sp0[r] += p;
          else if (dist >= 2) sp4[r] += p;
          else if (dist == -1) sv1[r] += p;
          else if (dist == 0) sv2[r] += p;
          else sv3[r] += p;
          Ps[w][g * 4 + r][n * 16 + lr] = f2bf_rna(p);
        }
      }
    }
    // Compiler fence: forbid hoisting the short8 Ps loads above the scalar
    // ushort Ps stores (TBAA). Same-wave DS ops complete in order in HW.
    asm volatile("" ::: "memory");
    short8 vf[4][2];
#pragma unroll
    for (int n = 0; n < 4; ++n)
#pragma unroll
      for (int h2 = 0; h2 < 2; ++h2)
        vf[n][h2] = *reinterpret_cast<const short8*>(
            &Vs[(n * 16 + lr) * 64 + (((g + 4 * h2) ^ (lr & 7)) * 8)]);
    short8 pa0 = *reinterpret_cast<const short8*>(&Ps[w][lr][g * 8]);
    short8 pa1 = *reinterpret_cast<const short8*>(&Ps[w][lr][g * 8 + 32]);
    __builtin_amdgcn_s_setprio(1);  // T5: PV cluster
#pragma unroll
    for (int n = 0; n < 4; ++n) {
      accO[n] = mfma16(pa0, vf[n][0], accO[n]);
      accO[n] = mfma16(pa1, vf[n][1], accO[n]);
    }
    __builtin_amdgcn_s_setprio(0);
    __syncthreads();  // all waves done with this buffer; next-tile staging drained
  }

  // ---- epilogue: reduce bucket sums over the 16-lane group, write output ----
#pragma unroll
  for (int i = 0; i < 4; ++i) {
    float v0 = sp0[i], v1 = sv1[i], v2 = sv2[i], v3 = sv3[i], v4 = sp4[i];
#pragma unroll
    for (int s = 1; s <= 8; s <<= 1) {
      v0 += __shfl_xor(v0, s); v1 += __shfl_xor(v1, s); v2 += __shfl_xor(v2, s);
      v3 += __shfl_xor(v3, s); v4 += __shfl_xor(v4, s);
    }
    const float rl = 1.f / (v0 + v1 + v2 + v3 + v4);
    const int qrow = b * S_LEN + qbase + w * 16 + g * 4 + i;
#pragma unroll
    for (int n = 0; n < 4; ++n) {
      const int d = n * 16 + lr;
      const float val = (accO[n][i] + v0 * rvs[0][d] + v1 * rvs[1][d] +
                         v2 * rvs[2][d] + v3 * rvs[3][d] + v4 * rvs[4][d]) * rl;
      Xa[(size_t)qrow * HID_DIM + h * HD + d] = f2bf(val);
    }
  }
}

extern "C" void kernel_launch(void* const* d_in, const int* in_sizes, int n_in,
                              void* d_out, int out_size, void* d_ws, size_t ws_size,
                              hipStream_t stream) {
  (void)in_sizes; (void)n_in; (void)out_size; (void)ws_size;
  const float* f_key   = (const float*)d_in[0];
  const float* f_query = (const float*)d_in[1];
  const float* f_value = (const float*)d_in[2];
  const float* Wq = (const float*)d_in[3];
  const float* bq = (const float*)d_in[4];
  const float* Wk = (const float*)d_in[5];
  const float* bk = (const float*)d_in[6];
  const float* Wv = (const float*)d_in[7];
  const float* bv = (const float*)d_in[8];
  const float* Wo = (const float*)d_in[9];
  const float* bo = (const float*)d_in[10];
  const float* relk = (const float*)d_in[11];
  const float* relv = (const float*)d_in[12];

  char* ws = (char*)d_ws;
  const size_t SZ = (size_t)MTOT * HID_DIM * sizeof(unsigned short);  // 8 MiB
  unsigned short* cq  = (unsigned short*)(ws + 0 * SZ);
  unsigned short* ck  = (unsigned short*)(ws + 1 * SZ);
  unsigned short* cv  = (unsigned short*)(ws + 2 * SZ);
  unsigned short* wqb = (unsigned short*)(ws + 3 * SZ);
  unsigned short* wkb = wqb + 1024 * 1024;
  unsigned short* wvb = wkb + 1024 * 1024;
  unsigned short* wob = wvb + 1024 * 1024;
  unsigned short* Qp  = (unsigned short*)(ws + 4 * SZ);
  unsigned short* Kp  = (unsigned short*)(ws + 5 * SZ);
  unsigned short* Vt  = (unsigned short*)(ws + 6 * SZ);
  unsigned short* xa  = cq;  // cq dead after qkv_gemm

  cvt_all<<<dim3(2048), dim3(256), 0, stream>>>(f_query, f_key, f_value, Wq, Wk, Wv, Wo,
                                                cq, ck, cv, wqb, wkb, wvb, wob);
  qkv_gemm<<<dim3(768), dim3(256), 0, stream>>>(cq, ck, cv, wqb, wkb, wvb, bq, bk, bv,
                                                Qp, Kp, Vt);
  attn_kernel<<<dim3(512), dim3(512), 0, stream>>>(Qp, Kp, Vt, relk, relv, xa);
  out_gemm<<<dim3(256), dim3(512), 0, stream>>>(xa, wob, bo, (float*)d_out);
}

// Round 20
// 140.072 us; speedup vs baseline: 1.0171x; 1.0171x over previous
//
#include <hip/hip_runtime.h>
#include <hip/hip_bf16.h>

#define S_LEN 2048
#define HID_DIM 1024
#define NH 16
#define HD 64
#define MTOT 4096  // B*S

typedef __attribute__((ext_vector_type(8))) short short8;
typedef __attribute__((ext_vector_type(4))) float f32x4;

__device__ __forceinline__ float bf2f(unsigned short u) {
  union { unsigned int i; float f; } x; x.i = ((unsigned int)u) << 16; return x.f;
}
__device__ __forceinline__ unsigned short f2bf(float f) {
  union { float ff; unsigned int i; } x; x.ff = f;
  return (unsigned short)((x.i + 0x7fffu + ((x.i >> 16) & 1u)) >> 16);
}
__device__ __forceinline__ unsigned short f2bf_rna(float f) {  // f >= 0 only
  union { float ff; unsigned int i; } x; x.ff = f;
  return (unsigned short)((x.i + 0x8000u) >> 16);
}
__device__ __forceinline__ f32x4 mfma16(short8 a, short8 b, f32x4 c) {
  return __builtin_amdgcn_mfma_f32_16x16x32_bf16(a, b, c, 0, 0, 0);
}
__device__ __forceinline__ void gl_lds16(const unsigned short* g, unsigned short* l) {
  __builtin_amdgcn_global_load_lds(
      (const __attribute__((address_space(1))) unsigned int*)g,
      (__attribute__((address_space(3))) unsigned int*)l, 16, 0, 0);
}

// ---------------- single fused f32 -> bf16 convert (grid-stride, 7 buffers) ----------------
#define CVT_N4 4194304
__global__ __launch_bounds__(256) void cvt_all(
    const float* __restrict__ fq, const float* __restrict__ fk, const float* __restrict__ fv,
    const float* __restrict__ Wq, const float* __restrict__ Wk, const float* __restrict__ Wv,
    const float* __restrict__ Wo,
    unsigned short* __restrict__ cq, unsigned short* __restrict__ ck,
    unsigned short* __restrict__ cv, unsigned short* __restrict__ wqb,
    unsigned short* __restrict__ wkb, unsigned short* __restrict__ wvb,
    unsigned short* __restrict__ wob) {
  for (int i = blockIdx.x * 256 + threadIdx.x; i < CVT_N4; i += gridDim.x * 256) {
    const float4* s; unsigned long long* d; int off;
    if (i < 3145728) {
      if (i < 1048576)      { s = (const float4*)fq; d = (unsigned long long*)cq; off = i; }
      else if (i < 2097152) { s = (const float4*)fk; d = (unsigned long long*)ck; off = i - 1048576; }
      else                  { s = (const float4*)fv; d = (unsigned long long*)cv; off = i - 2097152; }
    } else {
      const int wi = i - 3145728;
      if (wi < 262144)      { s = (const float4*)Wq; d = (unsigned long long*)wqb; off = wi; }
      else if (wi < 524288) { s = (const float4*)Wk; d = (unsigned long long*)wkb; off = wi - 262144; }
      else if (wi < 786432) { s = (const float4*)Wv; d = (unsigned long long*)wvb; off = wi - 524288; }
      else                  { s = (const float4*)Wo; d = (unsigned long long*)wob; off = wi - 786432; }
    }
    float4 v = s[off];
    union { unsigned short u[4]; unsigned long long ll; } o;
    o.u[0] = f2bf(v.x); o.u[1] = f2bf(v.y); o.u[2] = f2bf(v.z); o.u[3] = f2bf(v.w);
    d[off] = o.ll;
  }
}

// ---------------- GEMM core: C[128x128] += A[128xK] * W[128xK]^T ----------------
__device__ __forceinline__ void gemm_core(const unsigned short* __restrict__ A,
                                          const unsigned short* __restrict__ W,
                                          unsigned short* As, unsigned short* Bs,
                                          int m0, int n0, f32x4 (&acc)[4][4]) {
  const int tid = threadIdx.x;
  const int lane = tid & 63;
  const int wrow = (tid >> 6) >> 1, wcol = (tid >> 6) & 1;
  const int lr = lane & 15, g = lane >> 4;
  const int r32 = tid >> 3;                     // 0..31
  const int cph = (tid & 7) ^ (r32 & 7);        // swizzled source chunk
  const unsigned short* ag = A + (size_t)(m0 + r32) * HID_DIM + cph * 8;
  const unsigned short* bg = W + (size_t)(n0 + r32) * HID_DIM + cph * 8;
  unsigned short* al = As + tid * 8;
  unsigned short* bl = Bs + tid * 8;
  for (int k0 = 0; k0 < HID_DIM; k0 += 64) {
    __syncthreads();
#pragma unroll
    for (int p = 0; p < 4; ++p) {
      gl_lds16(ag + (size_t)(p * 32) * HID_DIM + k0, al + p * 2048);
      gl_lds16(bg + (size_t)(p * 32) * HID_DIM + k0, bl + p * 2048);
    }
    __syncthreads();
#pragma unroll
    for (int ks = 0; ks < 2; ++ks) {
      short8 af[4], bfr[4];
#pragma unroll
      for (int m = 0; m < 4; ++m)
        af[m] = *reinterpret_cast<const short8*>(
            &As[(wrow * 64 + m * 16 + lr) * 64 + (((ks * 4 + g) ^ (lr & 7)) * 8)]);
#pragma unroll
      for (int n = 0; n < 4; ++n)
        bfr[n] = *reinterpret_cast<const short8*>(
            &Bs[(wcol * 64 + n * 16 + lr) * 64 + (((ks * 4 + g) ^ (lr & 7)) * 8)]);
#pragma unroll
      for (int m = 0; m < 4; ++m)
#pragma unroll
        for (int n = 0; n < 4; ++n)
          acc[m][n] = mfma16(af[m], bfr[n], acc[m][n]);
    }
  }
}

// ---------------- fused QKV projection GEMM (Q pre-scaled by log2e/8) ----------------
__global__ __launch_bounds__(256, 4) void qkv_gemm(
    const unsigned short* __restrict__ Aq, const unsigned short* __restrict__ Ak,
    const unsigned short* __restrict__ Av,
    const unsigned short* __restrict__ Wq, const unsigned short* __restrict__ Wk,
    const unsigned short* __restrict__ Wv,
    const float* __restrict__ bq, const float* __restrict__ bk, const float* __restrict__ bv,
    unsigned short* __restrict__ Qp, unsigned short* __restrict__ Kp,
    unsigned short* __restrict__ Vt) {
  __shared__ __attribute__((aligned(16))) unsigned short As[128 * 64];
  __shared__ __attribute__((aligned(16))) unsigned short Bs[128 * 64];
  const int bid = blockIdx.x;            // 0..767
  const int xcd = bid & 7;
  const int j = bid >> 3;                // 0..95 local to XCD
  const int G = xcd * 12 + (j >> 3);     // global (which,m0) group 0..95
  const int which = G >> 5;              // 0:Q 1:K 2:V
  const int m0 = (G & 31) * 128;
  const int n0 = (j & 7) * 128;
  const unsigned short* A = which == 0 ? Aq : which == 1 ? Ak : Av;
  const unsigned short* W = which == 0 ? Wq : which == 1 ? Wk : Wv;
  const float* bias = which == 0 ? bq : which == 1 ? bk : bv;

  f32x4 acc[4][4];
  const f32x4 vzero = {0.f, 0.f, 0.f, 0.f};
#pragma unroll
  for (int m = 0; m < 4; ++m)
#pragma unroll
    for (int n = 0; n < 4; ++n) acc[m][n] = vzero;

  gemm_core(A, W, As, Bs, m0, n0, acc);

  const int lane = threadIdx.x & 63;
  const int wrow = (threadIdx.x >> 6) >> 1, wcol = (threadIdx.x >> 6) & 1;
  const int lr = lane & 15, g = lane >> 4;
  const float scl = (which == 0) ? 0.125f * 1.44269504f : 1.0f;
#pragma unroll
  for (int m = 0; m < 4; ++m) {
    const int rbase = m0 + wrow * 64 + m * 16 + g * 4;
#pragma unroll
    for (int n = 0; n < 4; ++n) {
      const int col = n0 + wcol * 64 + n * 16 + lr;
      const float bcol = bias[col];
      if (which < 2) {
        unsigned short* O = which == 0 ? Qp : Kp;
#pragma unroll
        for (int rg = 0; rg < 4; ++rg)
          O[(size_t)(rbase + rg) * HID_DIM + col] = f2bf((acc[m][n][rg] + bcol) * scl);
      } else {
        const int bb = rbase >> 11, s = rbase & 2047;
        const int h = col >> 6, d = col & 63;
        union { unsigned short u[4]; unsigned long long ll; } o;
#pragma unroll
        for (int rg = 0; rg < 4; ++rg) o.u[rg] = f2bf(acc[m][n][rg] + bcol);
        *reinterpret_cast<unsigned long long*>(
            &Vt[((size_t)(bb * NH + h) * HD + d) * S_LEN + s]) = o.ll;
      }
    }
  }
}

// ---------------- output GEMM: 512-thread / 8-wave blocks (2x4 wave grid) ----------------
__global__ __launch_bounds__(512) void out_gemm(const unsigned short* __restrict__ X,
                                                const unsigned short* __restrict__ Wo,
                                                const float* __restrict__ bo,
                                                float* __restrict__ out) {
  __shared__ __attribute__((aligned(16))) unsigned short As[128 * 64];
  __shared__ __attribute__((aligned(16))) unsigned short Bs[128 * 64];
  const int bid = blockIdx.x;            // 0..255
  const int xcd = bid & 7;
  const int j = bid >> 3;                // 0..31
  const int m0 = (xcd * 4 + (j >> 3)) * 128;
  const int n0 = (j & 7) * 128;
  const int tid = threadIdx.x;
  const int lane = tid & 63;
  const int w = tid >> 6;                // 0..7
  const int wrow = w >> 2;               // 0..1 : 64-row half
  const int wcol = w & 3;                // 0..3 : 32-col quarter
  const int lr = lane & 15, g = lane >> 4;

  f32x4 acc[4][2];
  const f32x4 vzero = {0.f, 0.f, 0.f, 0.f};
#pragma unroll
  for (int m = 0; m < 4; ++m)
#pragma unroll
    for (int n = 0; n < 2; ++n) acc[m][n] = vzero;

  for (int k0 = 0; k0 < HID_DIM; k0 += 64) {
    __syncthreads();
#pragma unroll
    for (int p = 0; p < 2; ++p) {
      const int ci = p * 512 + tid;      // chunk index 0..1023
      const int row = ci >> 3, c = ci & 7;
      const int csrc = (c ^ (row & 7)) * 8;
      gl_lds16(X + (size_t)(m0 + row) * HID_DIM + csrc + k0, As + ci * 8);
      gl_lds16(Wo + (size_t)(n0 + row) * HID_DIM + csrc + k0, Bs + ci * 8);
    }
    __syncthreads();
#pragma unroll
    for (int ks = 0; ks < 2; ++ks) {
      short8 af[4], bfr[2];
#pragma unroll
      for (int m = 0; m < 4; ++m)
        af[m] = *reinterpret_cast<const short8*>(
            &As[(wrow * 64 + m * 16 + lr) * 64 + (((ks * 4 + g) ^ (lr & 7)) * 8)]);
#pragma unroll
      for (int n = 0; n < 2; ++n)
        bfr[n] = *reinterpret_cast<const short8*>(
            &Bs[(wcol * 32 + n * 16 + lr) * 64 + (((ks * 4 + g) ^ (lr & 7)) * 8)]);
#pragma unroll
      for (int m = 0; m < 4; ++m)
#pragma unroll
        for (int n = 0; n < 2; ++n)
          acc[m][n] = mfma16(af[m], bfr[n], acc[m][n]);
    }
  }

#pragma unroll
  for (int m = 0; m < 4; ++m) {
    const int rbase = m0 + wrow * 64 + m * 16 + g * 4;
#pragma unroll
    for (int n = 0; n < 2; ++n) {
      const int col = n0 + wcol * 32 + n * 16 + lr;
      const float bcol = bo[col];
#pragma unroll
      for (int rg = 0; rg < 4; ++rg)
        out[(size_t)(rbase + rg) * HID_DIM + col] = acc[m][n][rg] + bcol;
    }
  }
}

// ---------------- flash attention: MFMA-based projs prologue + native exp2 ----------------
__global__ __launch_bounds__(512, 2) void attn_kernel(
    const unsigned short* __restrict__ Qp, const unsigned short* __restrict__ Kp,
    const unsigned short* __restrict__ Vt, const float* __restrict__ relk,
    const float* __restrict__ relv, unsigned short* __restrict__ Xa) {
  __shared__ __attribute__((aligned(16))) unsigned short kv[2][8192];  // [buf][K 4096sh | V 4096sh]
  __shared__ __attribute__((aligned(16))) unsigned short Ps[8][16][72];
  __shared__ float projs[128][5];
  __shared__ float rvs[5][64];

  const int tid = threadIdx.x;
  const int lane = tid & 63;
  const int w = tid >> 6;          // 0..7
  const int lr = lane & 15, g = lane >> 4;
  const int virt = (blockIdx.x & 7) * 64 + (blockIdx.x >> 3);
  const int bh = virt >> 4;
  const int qbase = (virt & 15) * 128;
  const int b = bh >> 4, h = bh & 15;

  const unsigned short* Qg = Qp + ((size_t)(b * S_LEN + qbase)) * HID_DIM + h * HD;
  const unsigned short* Kg = Kp + ((size_t)b * S_LEN) * HID_DIM + h * HD;
  const unsigned short* Vg = Vt + (size_t)bh * HD * S_LEN;

  // ---- prologue: Q -> kv[1] (128 rows), K0/V0 -> kv[0]; swizzled-source gl_lds ----
#pragma unroll
  for (int i = 0; i < 2; ++i) {
    const int flat = i * 8192 + tid * 16;  // LDS byte
    const int row = flat >> 7, c = (flat >> 4) & 7;
    gl_lds16(Qg + (size_t)row * HID_DIM + ((c ^ (row & 7)) * 8), &kv[1][flat >> 1]);
  }
  {
    const int flat = tid * 16;             // 8 KB = one pass with 512 threads
    const int row = flat >> 7, c = (flat >> 4) & 7;
    const int csrc = (c ^ (row & 7)) * 8;
    gl_lds16(Kg + (size_t)row * HID_DIM + csrc, &kv[0][flat >> 1]);
    gl_lds16(Vg + (size_t)row * S_LEN + csrc, &kv[0][4096 + (flat >> 1)]);
  }
  for (int i = tid; i < 320; i += 512) ((float*)rvs)[i] = relv[i];
  __syncthreads();  // Q, K0, V0 staged (barrier drains vmcnt)

  // A-fragments of Q
  short8 aq[2];
#pragma unroll
  for (int h2 = 0; h2 < 2; ++h2) {
    const int row = w * 16 + lr;
    aq[h2] = *reinterpret_cast<const short8*>(
        &kv[1][row * 64 + (((g + 4 * h2) ^ (lr & 7)) * 8)]);
  }
  // projs via MFMA (B = relk rows j=lr<5, bf16; zero otherwise)
  {
    short8 rk0 = {0, 0, 0, 0, 0, 0, 0, 0}, rk1 = rk0;
    if (lr < 5) {
      const float* rp = relk + lr * 64 + g * 8;
#pragma unroll
      for (int e = 0; e < 8; ++e) {
        rk0[e] = (short)f2bf(rp[e]);
        rk1[e] = (short)f2bf(rp[e + 32]);
      }
    }
    const f32x4 vz = {0.f, 0.f, 0.f, 0.f};
    f32x4 pacc = mfma16(aq[0], rk0, vz);
    pacc = mfma16(aq[1], rk1, pacc);
    if (lr < 5) {
#pragma unroll
      for (int r = 0; r < 4; ++r) projs[w * 16 + g * 4 + r][lr] = pacc[r];
    }
  }
  __syncthreads();  // projs visible; Q reads done (kv[1] overwritten at t=0)

  float pj0[4], pj4[4];
#pragma unroll
  for (int i = 0; i < 4; ++i) {
    const int qloc = w * 16 + g * 4 + i;
    pj0[i] = projs[qloc][0];
    pj4[i] = projs[qloc][4];
  }
  f32x4 cinitL, cinitR;
#pragma unroll
  for (int i = 0; i < 4; ++i) { cinitL[i] = pj0[i]; cinitR[i] = pj4[i]; }

  const f32x4 vzero = {0.f, 0.f, 0.f, 0.f};
  f32x4 accO[4];
#pragma unroll
  for (int n = 0; n < 4; ++n) accO[n] = vzero;
  float sp0[4], sp4[4], sv1[4], sv2[4], sv3[4];
#pragma unroll
  for (int i = 0; i < 4; ++i) {
    sp0[i] = 0.f; sp4[i] = 0.f; sv1[i] = 0.f; sv2[i] = 0.f; sv3[i] = 0.f;
  }
  const int Qw = qbase + w * 16;  // wave's first q row (global)

  for (int t = 0; t < 32; ++t) {
    const int kb = t * 64;
    const unsigned short* Ks = kv[t & 1];
    const unsigned short* Vs = Ks + 4096;
    if (t < 31) {  // prefetch next tile into other buffer
      const int kb2 = kb + 64;
      unsigned short* dst = &kv[(t + 1) & 1][0];
      const int flat = tid * 16;
      const int row = flat >> 7, c = (flat >> 4) & 7;
      const int csrc = (c ^ (row & 7)) * 8;
      gl_lds16(Kg + (size_t)(kb2 + row) * HID_DIM + csrc, dst + (flat >> 1));
      gl_lds16(Vg + (size_t)row * S_LEN + kb2 + csrc, dst + 4096 + (flat >> 1));
    }
    const bool mixed = (kb + 63 >= Qw - 2) && (kb <= Qw + 17);
    const bool left = kb < Qw;
    const f32x4 ci = mixed ? vzero : (left ? cinitL : cinitR);
    // K fragments + QK^T (pj pre-added via C-init on non-mixed tiles)
    short8 kf[4][2];
#pragma unroll
    for (int n = 0; n < 4; ++n)
#pragma unroll
      for (int h2 = 0; h2 < 2; ++h2)
        kf[n][h2] = *reinterpret_cast<const short8*>(
            &Ks[(n * 16 + lr) * 64 + (((g + 4 * h2) ^ (lr & 7)) * 8)]);
    f32x4 accS[4];
#pragma unroll
    for (int n = 0; n < 4; ++n) {
      f32x4 z = mfma16(aq[0], kf[n][0], ci);
      accS[n] = mfma16(aq[1], kf[n][1], z);
    }

    if (!mixed) {
#pragma unroll
      for (int n = 0; n < 4; ++n)
#pragma unroll
        for (int r = 0; r < 4; ++r) {
          // raw v_exp_f32 (log2e folded into Q); NOT exp2f (libm precise = ~6 ops)
          const float p = __builtin_amdgcn_exp2f(accS[n][r]);
          if (left) sp0[r] += p; else sp4[r] += p;
          Ps[w][g * 4 + r][n * 16 + lr] = f2bf_rna(p);
        }
    } else {
#pragma unroll
      for (int n = 0; n < 4; ++n) {
        const int kg = kb + n * 16 + lr;
#pragma unroll
        for (int r = 0; r < 4; ++r) {
          const int qloc = w * 16 + g * 4 + r;
          const int dist = kg - (qbase + qloc);
          float pjv;
          if (dist <= -2) pjv = pj0[r];
          else if (dist >= 2) pjv = pj4[r];
          else pjv = projs[qloc][dist + 2];
          const float p = __builtin_amdgcn_exp2f(accS[n][r] + pjv);
          if (dist <= -2) sp0[r] += p;
          else if (dist >= 2) sp4[r] += p;
          else if (dist == -1) sv1[r] += p;
          else if (dist == 0) sv2[r] += p;
          else sv3[r] += p;
          Ps[w][g * 4 + r][n * 16 + lr] = f2bf_rna(p);
        }
      }
    }
    // Compiler fence: forbid hoisting the short8 Ps loads above the scalar
    // ushort Ps stores (TBAA). Same-wave DS ops complete in order in HW.
    asm volatile("" ::: "memory");
    // V fragments, P fragments, PV (batched for ILP)
    short8 vf[4][2];
#pragma unroll
    for (int n = 0; n < 4; ++n)
#pragma unroll
      for (int h2 = 0; h2 < 2; ++h2)
        vf[n][h2] = *reinterpret_cast<const short8*>(
            &Vs[(n * 16 + lr) * 64 + (((g + 4 * h2) ^ (lr & 7)) * 8)]);
    short8 pa0 = *reinterpret_cast<const short8*>(&Ps[w][lr][g * 8]);
    short8 pa1 = *reinterpret_cast<const short8*>(&Ps[w][lr][g * 8 + 32]);
#pragma unroll
    for (int n = 0; n < 4; ++n) {
      accO[n] = mfma16(pa0, vf[n][0], accO[n]);
      accO[n] = mfma16(pa1, vf[n][1], accO[n]);
    }
    __syncthreads();  // all waves done with this buffer; next-tile staging drained
  }

  // ---- epilogue: reduce bucket sums over the 16-lane group, write output ----
#pragma unroll
  for (int i = 0; i < 4; ++i) {
    float v0 = sp0[i], v1 = sv1[i], v2 = sv2[i], v3 = sv3[i], v4 = sp4[i];
#pragma unroll
    for (int s = 1; s <= 8; s <<= 1) {
      v0 += __shfl_xor(v0, s); v1 += __shfl_xor(v1, s); v2 += __shfl_xor(v2, s);
      v3 += __shfl_xor(v3, s); v4 += __shfl_xor(v4, s);
    }
    const float rl = 1.f / (v0 + v1 + v2 + v3 + v4);
    const int qrow = b * S_LEN + qbase + w * 16 + g * 4 + i;
#pragma unroll
    for (int n = 0; n < 4; ++n) {
      const int d = n * 16 + lr;
      const float val = (accO[n][i] + v0 * rvs[0][d] + v1 * rvs[1][d] +
                         v2 * rvs[2][d] + v3 * rvs[3][d] + v4 * rvs[4][d]) * rl;
      Xa[(size_t)qrow * HID_DIM + h * HD + d] = f2bf(val);
    }
  }
}

extern "C" void kernel_launch(void* const* d_in, const int* in_sizes, int n_in,
                              void* d_out, int out_size, void* d_ws, size_t ws_size,
                              hipStream_t stream) {
  (void)in_sizes; (void)n_in; (void)out_size; (void)ws_size;
  const float* f_key   = (const float*)d_in[0];
  const float* f_query = (const float*)d_in[1];
  const float* f_value = (const float*)d_in[2];
  const float* Wq = (const float*)d_in[3];
  const float* bq = (const float*)d_in[4];
  const float* Wk = (const float*)d_in[5];
  const float* bk = (const float*)d_in[6];
  const float* Wv = (const float*)d_in[7];
  const float* bv = (const float*)d_in[8];
  const float* Wo = (const float*)d_in[9];
  const float* bo = (const float*)d_in[10];
  const float* relk = (const float*)d_in[11];
  const float* relv = (const float*)d_in[12];

  char* ws = (char*)d_ws;
  const size_t SZ = (size_t)MTOT * HID_DIM * sizeof(unsigned short);  // 8 MiB
  unsigned short* cq  = (unsigned short*)(ws + 0 * SZ);
  unsigned short* ck  = (unsigned short*)(ws + 1 * SZ);
  unsigned short* cv  = (unsigned short*)(ws + 2 * SZ);
  unsigned short* wqb = (unsigned short*)(ws + 3 * SZ);
  unsigned short* wkb = wqb + 1024 * 1024;
  unsigned short* wvb = wkb + 1024 * 1024;
  unsigned short* wob = wvb + 1024 * 1024;
  unsigned short* Qp  = (unsigned short*)(ws + 4 * SZ);
  unsigned short* Kp  = (unsigned short*)(ws + 5 * SZ);
  unsigned short* Vt  = (unsigned short*)(ws + 6 * SZ);
  unsigned short* xa  = cq;  // cq dead after qkv_gemm

  cvt_all<<<dim3(2048), dim3(256), 0, stream>>>(f_query, f_key, f_value, Wq, Wk, Wv, Wo,
                                                cq, ck, cv, wqb, wkb, wvb, wob);
  qkv_gemm<<<dim3(768), dim3(256), 0, stream>>>(cq, ck, cv, wqb, wkb, wvb, bq, bk, bv,
                                                Qp, Kp, Vt);
  attn_kernel<<<dim3(512), dim3(512), 0, stream>>>(Qp, Kp, Vt, relk, relv, xa);
  out_gemm<<<dim3(256), dim3(512), 0, stream>>>(xa, wob, bo, (float*)d_out);
}